// Round 1
// baseline (868.248 us; speedup 1.0000x reference)
//
#include <hip/hip_runtime.h>
#include <math.h>

// Problem constants (from reference)
constexpr int B_   = 2;
constexpr int S_   = 2048;
constexpr int HID_ = 512;
constexpr int H_   = 8;
constexpr int DH_  = 64;
constexpr int M_   = B_ * S_;   // 4096 rows for all GEMMs

// ---------------------------------------------------------------------------
// GEMM: C(M,N) = A(M,K) * W(N,K)^T + bias(N)     (M=4096, N=K=512)
// 64x64 tile, BK=16, 256 threads, 4x4 microtile, float4 LDS reads.
// HEADOUT: write into [b][h][s][dh] layout (for q/k/v heads); else plain [m][n].
// ---------------------------------------------------------------------------
template <bool HEADOUT>
__device__ __forceinline__ void gemm_body(const float* __restrict__ A,
                                          const float* __restrict__ W,
                                          const float* __restrict__ bias,
                                          float* __restrict__ out)
{
    constexpr int K_ = HID_;
    // stored transposed [k][m], padded to 68 floats (16B-aligned rows, bank-spread)
    __shared__ __align__(16) float As[16][68];
    __shared__ __align__(16) float Ws[16][68];

    const int t  = threadIdx.x;
    const int tx = t & 15;   // n-dir
    const int ty = t >> 4;   // m-dir
    const int bm = blockIdx.x * 64;
    const int bn = blockIdx.y * 64;

    float acc[4][4];
#pragma unroll
    for (int i = 0; i < 4; ++i)
#pragma unroll
        for (int j = 0; j < 4; ++j) acc[i][j] = 0.f;

    for (int k0 = 0; k0 < K_; k0 += 16) {
        __syncthreads();
#pragma unroll
        for (int i = 0; i < 4; ++i) {
            const int flat = t + i * 256;   // 0..1023
            const int row  = flat >> 4;     // 0..63  (tile m / n)
            const int col  = flat & 15;     // 0..15  (tile k)
            As[col][row] = A[(size_t)(bm + row) * K_ + k0 + col];
            Ws[col][row] = W[(size_t)(bn + row) * K_ + k0 + col];
        }
        __syncthreads();
#pragma unroll
        for (int kk = 0; kk < 16; ++kk) {
            const float4 av = *(const float4*)&As[kk][ty * 4];
            const float4 wv = *(const float4*)&Ws[kk][tx * 4];
            const float a_[4] = {av.x, av.y, av.z, av.w};
            const float w_[4] = {wv.x, wv.y, wv.z, wv.w};
#pragma unroll
            for (int i = 0; i < 4; ++i)
#pragma unroll
                for (int j = 0; j < 4; ++j)
                    acc[i][j] = fmaf(a_[i], w_[j], acc[i][j]);
        }
    }

#pragma unroll
    for (int i = 0; i < 4; ++i) {
        const int m = bm + ty * 4 + i;
#pragma unroll
        for (int j = 0; j < 4; ++j) {
            const int n   = bn + tx * 4 + j;
            const float val = acc[i][j] + bias[n];
            if (HEADOUT) {
                const int b = m >> 11;          // / S_
                const int s = m & (S_ - 1);
                const int h = n >> 6;           // / DH_
                const int d = n & (DH_ - 1);
                out[(((size_t)b * H_ + h) * S_ + s) * DH_ + d] = val;
            } else {
                out[(size_t)m * HID_ + n] = val;
            }
        }
    }
}

struct QkvPtrs {
    const float* A[3];
    const float* W[3];
    const float* bias[3];
    float*       out[3];
};

__global__ __launch_bounds__(256)
void gemm_qkv_kernel(QkvPtrs p)
{
    const int z = blockIdx.z;   // 0=q 1=k 2=v
    gemm_body<true>(p.A[z], p.W[z], p.bias[z], p.out[z]);
}

__global__ __launch_bounds__(256)
void gemm_out_kernel(const float* __restrict__ A, const float* __restrict__ W,
                     const float* __restrict__ bias, float* __restrict__ out)
{
    gemm_body<false>(A, W, bias, out);
}

// ---------------------------------------------------------------------------
// EulerFormer rotation, in-place on [B][H][S][DH] tensors (q then k).
// pair idx -> (i = dim-pair 0..31, s = seq pos). alpha = s * 10000^(-i/32).
// Accurate sincosf/atan2f: theta can be ~2000 rad; fast-path v_sin range
// reduction would cost ~1e-4 abs error vs the fp32 reference.
// ---------------------------------------------------------------------------
__global__ __launch_bounds__(256)
void euler_rot_kernel(float* __restrict__ qh, float* __restrict__ kh,
                      const float* __restrict__ dq, const float* __restrict__ dk)
{
    constexpr int NP = B_ * H_ * S_ * (DH_ / 2);   // 1,048,576 pairs per tensor
    const int idx = blockIdx.x * 256 + threadIdx.x;

    float* x; float delta; int pi;
    if (idx < NP) { x = qh; delta = dq[0]; pi = idx; }
    else          { x = kh; delta = dk[0]; pi = idx - NP; }

    const int i = pi & 31;
    const int s = (pi >> 5) & (S_ - 1);

    // log2(10000)/32 = 0.4152410118609203
    const float freq = exp2f(-(float)i * 0.4152410118609203f);

    const float2 rp = ((const float2*)x)[pi];
    const float lam = sqrtf(rp.x * rp.x + rp.y * rp.y);
    const float th  = atan2f(rp.y, rp.x) * delta + (float)s * freq;
    float sn, cs;
    sincosf(th, &sn, &cs);
    ((float2*)x)[pi] = make_float2(lam * cs, lam * sn);
}

// ---------------------------------------------------------------------------
// Flash attention (causal), fp32. Grid = (S/64 q-tiles, B*H). Block = 256.
// Thread (r = t>>2, c = t&3): owns q-row r; computes scores for k-chunk
// [c*16, c*16+16); owns output dims [c*16, c*16+16).
// LDS: Q/K/V tiles 64x64 (float4, padded rows), score tile Ss 64x64.
// ---------------------------------------------------------------------------
__global__ __launch_bounds__(256)
void attn_kernel(const float* __restrict__ qh, const float* __restrict__ kh,
                 const float* __restrict__ vh, float* __restrict__ hidden)
{
    __shared__ float4 Qs[64][17];
    __shared__ float4 Ks[64][17];
    __shared__ float4 Vs[64][17];
    __shared__ __align__(16) float Ss[64][68];

    const int t  = threadIdx.x;
    const int r  = t >> 2;
    const int c  = t & 3;
    const int qt = blockIdx.x;      // q tile 0..31
    const int bh = blockIdx.y;      // 0..15

    const float4* Q4 = (const float4*)(qh + ((size_t)bh * S_ + (size_t)qt * 64) * DH_);
    const float4* K4 = (const float4*)(kh + (size_t)bh * S_ * DH_);
    const float4* V4 = (const float4*)(vh + (size_t)bh * S_ * DH_);

    // Q tile: 64 rows x 16 float4, fully contiguous
#pragma unroll
    for (int i = 0; i < 4; ++i) {
        const int flat = t + i * 256;
        Qs[flat >> 4][flat & 15] = Q4[flat];
    }

    float m = -INFINITY, l = 0.f;
    float O[16];
#pragma unroll
    for (int d = 0; d < 16; ++d) O[d] = 0.f;

    const int qg = qt * 64 + r;

    for (int kt = 0; kt <= qt; ++kt) {
        __syncthreads();   // previous iter done with Ks/Vs/Ss
#pragma unroll
        for (int i = 0; i < 4; ++i) {
            const int flat = t + i * 256;
            Ks[flat >> 4][flat & 15] = K4[(size_t)kt * 1024 + flat];
            Vs[flat >> 4][flat & 15] = V4[(size_t)kt * 1024 + flat];
        }
        __syncthreads();

        // QK^T for this thread's 16 k's
        float sc[16];
#pragma unroll
        for (int j = 0; j < 16; ++j) sc[j] = 0.f;
        for (int d4 = 0; d4 < 16; ++d4) {
            const float4 qv = Qs[r][d4];
#pragma unroll
            for (int j = 0; j < 16; ++j) {
                const float4 kv = Ks[c * 16 + j][d4];
                sc[j] += qv.x * kv.x + qv.y * kv.y + qv.z * kv.z + qv.w * kv.w;
            }
        }

        // scale + causal mask -> LDS score row
#pragma unroll
        for (int j = 0; j < 16; ++j) {
            const int kg = kt * 64 + c * 16 + j;
            Ss[r][c * 16 + j] = (kg <= qg) ? sc[j] * 0.125f : -INFINITY;
        }
        __syncthreads();

        // online softmax: row max (redundant x4 per row, consistent)
        float tmax = -INFINITY;
#pragma unroll
        for (int k4 = 0; k4 < 16; ++k4) {
            const float4 sv = *(const float4*)&Ss[r][k4 * 4];
            tmax = fmaxf(tmax, fmaxf(fmaxf(sv.x, sv.y), fmaxf(sv.z, sv.w)));
        }
        const float mnew = fmaxf(m, tmax);
        const float fac  = __expf(m - mnew);   // m=-inf first iter -> 0
#pragma unroll
        for (int d = 0; d < 16; ++d) O[d] *= fac;

        float lsum = 0.f;
        for (int k = 0; k < 64; ++k) {
            const float p = __expf(Ss[r][k] - mnew);  // masked -> exp(-inf)=0
            lsum += p;
            const float4 v0 = Vs[k][c * 4 + 0];
            const float4 v1 = Vs[k][c * 4 + 1];
            const float4 v2 = Vs[k][c * 4 + 2];
            const float4 v3 = Vs[k][c * 4 + 3];
            O[0]  += p * v0.x; O[1]  += p * v0.y; O[2]  += p * v0.z; O[3]  += p * v0.w;
            O[4]  += p * v1.x; O[5]  += p * v1.y; O[6]  += p * v1.z; O[7]  += p * v1.w;
            O[8]  += p * v2.x; O[9]  += p * v2.y; O[10] += p * v2.z; O[11] += p * v2.w;
            O[12] += p * v3.x; O[13] += p * v3.y; O[14] += p * v3.z; O[15] += p * v3.w;
        }
        l = l * fac + lsum;
        m = mnew;
    }

    const float inv = 1.f / l;
    const int b = bh >> 3;
    const int h = bh & 7;
    float* dst = hidden + ((size_t)b * S_ + qg) * HID_ + h * DH_ + c * 16;
#pragma unroll
    for (int d4 = 0; d4 < 4; ++d4) {
        const float4 o = make_float4(O[d4 * 4 + 0] * inv, O[d4 * 4 + 1] * inv,
                                     O[d4 * 4 + 2] * inv, O[d4 * 4 + 3] * inv);
        ((float4*)dst)[d4] = o;
    }
}

// ---------------------------------------------------------------------------
// Launch
// ---------------------------------------------------------------------------
extern "C" void kernel_launch(void* const* d_in, const int* in_sizes, int n_in,
                              void* d_out, int out_size, void* d_ws, size_t ws_size,
                              hipStream_t stream)
{
    const float* q  = (const float*)d_in[0];
    const float* k  = (const float*)d_in[1];
    const float* v  = (const float*)d_in[2];
    const float* Wq = (const float*)d_in[3];
    const float* bq = (const float*)d_in[4];
    const float* Wk = (const float*)d_in[5];
    const float* bk = (const float*)d_in[6];
    const float* Wv = (const float*)d_in[7];
    const float* bv = (const float*)d_in[8];
    const float* Wo = (const float*)d_in[9];
    const float* bo = (const float*)d_in[10];
    const float* dq = (const float*)d_in[11];
    const float* dk = (const float*)d_in[12];
    float* out = (float*)d_out;

    // workspace layout (fp32): qh | kh | vh | hidden, each B*S*HID = 2,097,152
    float* ws = (float*)d_ws;
    const size_t TEN = (size_t)B_ * S_ * HID_;
    float* qh     = ws;
    float* kh     = ws + TEN;
    float* vh     = ws + 2 * TEN;
    float* hidden = ws + 3 * TEN;

    QkvPtrs p;
    p.A[0] = q; p.W[0] = Wq; p.bias[0] = bq; p.out[0] = qh;
    p.A[1] = k; p.W[1] = Wk; p.bias[1] = bk; p.out[1] = kh;
    p.A[2] = v; p.W[2] = Wv; p.bias[2] = bv; p.out[2] = vh;

    gemm_qkv_kernel<<<dim3(M_ / 64, HID_ / 64, 3), 256, 0, stream>>>(p);
    euler_rot_kernel<<<(2 * B_ * H_ * S_ * (DH_ / 2)) / 256, 256, 0, stream>>>(qh, kh, dq, dk);
    attn_kernel<<<dim3(S_ / 64, B_ * H_), 256, 0, stream>>>(qh, kh, vh, hidden);
    gemm_out_kernel<<<dim3(M_ / 64, HID_ / 64), 256, 0, stream>>>(hidden, Wo, bo, out);
}

// Round 2
// 330.902 us; speedup vs baseline: 2.6239x; 2.6239x over previous
//
#include <hip/hip_runtime.h>
#include <math.h>

// Problem constants
constexpr int B_   = 2;
constexpr int S_   = 2048;
constexpr int HID_ = 512;
constexpr int H_   = 8;
constexpr int DH_  = 64;
constexpr int M_   = B_ * S_;

typedef unsigned short ushort_t;
typedef unsigned int   uint_t;
typedef __attribute__((ext_vector_type(4))) float  f32x4;
typedef __attribute__((ext_vector_type(8))) __bf16 bf16x8;
typedef __attribute__((ext_vector_type(4))) uint_t u32x4;

#define MFMA16(A, Bv, C) __builtin_amdgcn_mfma_f32_16x16x32_bf16( \
    __builtin_bit_cast(bf16x8, (A)), __builtin_bit_cast(bf16x8, (Bv)), (C), 0, 0, 0)

// Split fp32 x -> hi bf16 (truncate) + lo bf16 (truncate of exact residual).
// Packs two elements: returns {hi0|hi1<<16, lo0|lo1<<16}.
__device__ __forceinline__ uint2 splitPair(float x0, float x1) {
    uint_t b0 = __float_as_uint(x0), b1 = __float_as_uint(x1);
    uint_t hi = (b0 >> 16) | (b1 & 0xFFFF0000u);
    float h0 = __uint_as_float(b0 & 0xFFFF0000u);
    float h1 = __uint_as_float(b1 & 0xFFFF0000u);
    uint_t l0 = __float_as_uint(x0 - h0), l1 = __float_as_uint(x1 - h1);
    uint_t lo = (l0 >> 16) | (l1 & 0xFFFF0000u);
    return make_uint2(hi, lo);
}

// ---------------------------------------------------------------------------
// GEMM: C(M,N) = A(M,K) * W(N,K)^T + bias(N)   (M=4096, N=K=512), fp32 VALU.
// MODE 0: plain [m][n]; MODE 1: head [b][h][s][d]; MODE 2: head V-transposed
// [b][h][d][s]  (so attention can stage V^T with copy-shaped LDS writes).
// ---------------------------------------------------------------------------
template <int MODE>
__device__ __forceinline__ void gemm_body(const float* __restrict__ A,
                                          const float* __restrict__ W,
                                          const float* __restrict__ bias,
                                          float* __restrict__ out)
{
    constexpr int K_ = HID_;
    __shared__ __align__(16) float As[16][68];
    __shared__ __align__(16) float Ws[16][68];

    const int t  = threadIdx.x;
    const int tx = t & 15;
    const int ty = t >> 4;
    const int bm = blockIdx.x * 64;
    const int bn = blockIdx.y * 64;

    float acc[4][4];
#pragma unroll
    for (int i = 0; i < 4; ++i)
#pragma unroll
        for (int j = 0; j < 4; ++j) acc[i][j] = 0.f;

    for (int k0 = 0; k0 < K_; k0 += 16) {
        __syncthreads();
#pragma unroll
        for (int i = 0; i < 4; ++i) {
            const int flat = t + i * 256;
            const int row  = flat >> 4;
            const int col  = flat & 15;
            As[col][row] = A[(size_t)(bm + row) * K_ + k0 + col];
            Ws[col][row] = W[(size_t)(bn + row) * K_ + k0 + col];
        }
        __syncthreads();
#pragma unroll
        for (int kk = 0; kk < 16; ++kk) {
            const float4 av = *(const float4*)&As[kk][ty * 4];
            const float4 wv = *(const float4*)&Ws[kk][tx * 4];
            const float a_[4] = {av.x, av.y, av.z, av.w};
            const float w_[4] = {wv.x, wv.y, wv.z, wv.w};
#pragma unroll
            for (int i = 0; i < 4; ++i)
#pragma unroll
                for (int j = 0; j < 4; ++j)
                    acc[i][j] = fmaf(a_[i], w_[j], acc[i][j]);
        }
    }

#pragma unroll
    for (int i = 0; i < 4; ++i) {
        const int m = bm + ty * 4 + i;
#pragma unroll
        for (int j = 0; j < 4; ++j) {
            const int n   = bn + tx * 4 + j;
            const float val = acc[i][j] + bias[n];
            if (MODE == 0) {
                out[(size_t)m * HID_ + n] = val;
            } else {
                const int b = m >> 11;
                const int s = m & (S_ - 1);
                const int h = n >> 6;
                const int d = n & (DH_ - 1);
                if (MODE == 1)
                    out[(((size_t)b * H_ + h) * S_ + s) * DH_ + d] = val;
                else
                    out[(((size_t)b * H_ + h) * DH_ + d) * S_ + s] = val;
            }
        }
    }
}

struct QkvPtrs {
    const float* A[3];
    const float* W[3];
    const float* bias[3];
    float*       out[3];
};

__global__ __launch_bounds__(256)
void gemm_qkv_kernel(QkvPtrs p)
{
    const int z = blockIdx.z;   // 0=q 1=k 2=v
    if (z == 2) gemm_body<2>(p.A[2], p.W[2], p.bias[2], p.out[2]);
    else        gemm_body<1>(p.A[z], p.W[z], p.bias[z], p.out[z]);
}

__global__ __launch_bounds__(256)
void gemm_out_kernel(const float* __restrict__ A, const float* __restrict__ W,
                     const float* __restrict__ bias, float* __restrict__ out)
{
    gemm_body<0>(A, W, bias, out);
}

// ---------------------------------------------------------------------------
// Euler rotation, in-place on q/k head tensors ([b][h][s][dh]). Unchanged.
// ---------------------------------------------------------------------------
__global__ __launch_bounds__(256)
void euler_rot_kernel(float* __restrict__ qh, float* __restrict__ kh,
                      const float* __restrict__ dq, const float* __restrict__ dk)
{
    constexpr int NP = B_ * H_ * S_ * (DH_ / 2);
    const int idx = blockIdx.x * 256 + threadIdx.x;

    float* x; float delta; int pi;
    if (idx < NP) { x = qh; delta = dq[0]; pi = idx; }
    else          { x = kh; delta = dk[0]; pi = idx - NP; }

    const int i = pi & 31;
    const int s = (pi >> 5) & (S_ - 1);
    const float freq = exp2f(-(float)i * 0.4152410118609203f);  // 10000^(-i/32)

    const float2 rp = ((const float2*)x)[pi];
    const float lam = sqrtf(rp.x * rp.x + rp.y * rp.y);
    const float th  = atan2f(rp.y, rp.x) * delta + (float)s * freq;
    float sn, cs;
    sincosf(th, &sn, &cs);
    ((float2*)x)[pi] = make_float2(lam * cs, lam * sn);
}

// ---------------------------------------------------------------------------
// Flash attention (causal), split-bf16 MFMA (16x16x32), fp32 softmax.
// Grid (32, B*H), block 256 = 4 waves. Wave w owns q-rows [qt*64+w*16, +16).
// KV tile = 64 keys. K/V staged as split-bf16 in LDS (72-ushort rows: pad
// makes frag ds_read_b128 land 8 lanes per 4-bank group = conflict-free).
// P (post-softmax probs) round-trips via per-wave LDS planes so PV's A-frag
// (row = lane&15) can be read from QK's D layout (row = (lane>>4)*4+reg).
// Product x*y ~= xh*yh + xh*yl + xl*yh (3 MFMAs), rel err ~2^-16.
// ---------------------------------------------------------------------------
__global__ __launch_bounds__(256)
void attn_mfma_kernel(const float* __restrict__ qh, const float* __restrict__ kh,
                      const float* __restrict__ vt, float* __restrict__ hidden)
{
    __shared__ __align__(16) ushort_t Khi[64][72];
    __shared__ __align__(16) ushort_t Klo[64][72];
    __shared__ __align__(16) ushort_t Vhi[64][72];   // [dh][key]
    __shared__ __align__(16) ushort_t Vlo[64][72];
    __shared__ __align__(16) ushort_t Ph[4][16][72]; // per-wave [q][key]
    __shared__ __align__(16) ushort_t Pl[4][16][72];

    const int t    = threadIdx.x;
    const int lane = t & 63;
    const int wid  = t >> 6;
    const int a    = lane & 15;   // A-row / B-col / D-col index
    const int g    = lane >> 4;   // k-chunk group
    const int qt   = 31 - blockIdx.x;   // heavy tiles first (LPT)
    const int bh   = blockIdx.y;

    // Q fragments (A operand), scaled by 1/sqrt(DH), split hi/lo. Row = a.
    const float* Qrow = qh + ((size_t)bh * S_ + (size_t)qt * 64 + wid * 16 + a) * DH_;
    u32x4 qhi[2], qlo[2];
#pragma unroll
    for (int kit = 0; kit < 2; ++kit) {
        const float* p = Qrow + kit * 32 + g * 8;
        const float4 x0 = *(const float4*)p;
        const float4 x1 = *(const float4*)(p + 4);
        const uint2 p0 = splitPair(x0.x * 0.125f, x0.y * 0.125f);
        const uint2 p1 = splitPair(x0.z * 0.125f, x0.w * 0.125f);
        const uint2 p2 = splitPair(x1.x * 0.125f, x1.y * 0.125f);
        const uint2 p3 = splitPair(x1.z * 0.125f, x1.w * 0.125f);
        qhi[kit] = u32x4{p0.x, p1.x, p2.x, p3.x};
        qlo[kit] = u32x4{p0.y, p1.y, p2.y, p3.y};
    }

    f32x4 Oacc[4];
#pragma unroll
    for (int nt = 0; nt < 4; ++nt)
#pragma unroll
        for (int r = 0; r < 4; ++r) Oacc[nt][r] = 0.f;
    float mrow[4] = {-INFINITY, -INFINITY, -INFINITY, -INFINITY};
    float lrow[4] = {0.f, 0.f, 0.f, 0.f};

    const float4* Kg = (const float4*)(kh + (size_t)bh * S_ * DH_);  // [key][dh]
    const float*  Vg = vt + (size_t)bh * DH_ * S_;                   // [dh][s]

    for (int kt = 0; kt <= qt; ++kt) {
        __syncthreads();   // all waves done reading K/V of previous tile
        // ---- stage K tile: [key][dh] split-bf16
#pragma unroll
        for (int i = 0; i < 4; ++i) {
            const int flat = t + i * 256;
            const int key = flat >> 4, d4 = (flat & 15) * 4;
            const float4 kv = Kg[kt * 1024 + flat];
            const uint2 s01 = splitPair(kv.x, kv.y);
            const uint2 s23 = splitPair(kv.z, kv.w);
            *(uint2*)&Khi[key][d4] = make_uint2(s01.x, s23.x);
            *(uint2*)&Klo[key][d4] = make_uint2(s01.y, s23.y);
        }
        // ---- stage V tile: [dh][key] split-bf16 (global already transposed)
#pragma unroll
        for (int i = 0; i < 4; ++i) {
            const int flat = t + i * 256;
            const int dh = flat >> 4, k4 = (flat & 15) * 4;
            const float4 vv = *(const float4*)(Vg + (size_t)dh * S_ + kt * 64 + k4);
            const uint2 s01 = splitPair(vv.x, vv.y);
            const uint2 s23 = splitPair(vv.z, vv.w);
            *(uint2*)&Vhi[dh][k4] = make_uint2(s01.x, s23.x);
            *(uint2*)&Vlo[dh][k4] = make_uint2(s01.y, s23.y);
        }
        __syncthreads();

        // ---- QK^T: D[q=(g*4+r)][key=a+16nt], k-dim = dh
        f32x4 Sacc[4];
#pragma unroll
        for (int nt = 0; nt < 4; ++nt)
#pragma unroll
            for (int r = 0; r < 4; ++r) Sacc[nt][r] = 0.f;
#pragma unroll
        for (int kit = 0; kit < 2; ++kit) {
#pragma unroll
            for (int nt = 0; nt < 4; ++nt) {
                const u32x4 kbh = *(const u32x4*)&Khi[a + 16 * nt][kit * 32 + g * 8];
                const u32x4 kbl = *(const u32x4*)&Klo[a + 16 * nt][kit * 32 + g * 8];
                Sacc[nt] = MFMA16(qhi[kit], kbh, Sacc[nt]);
                Sacc[nt] = MFMA16(qhi[kit], kbl, Sacc[nt]);
                Sacc[nt] = MFMA16(qlo[kit], kbh, Sacc[nt]);
            }
        }

        // ---- causal mask + online softmax (row = q, uniform across 16-lane group)
        float sc[4][4];
        const int q0 = qt * 64 + wid * 16 + g * 4;   // + r = global q row
        const int k0 = kt * 64 + a;
#pragma unroll
        for (int nt = 0; nt < 4; ++nt)
#pragma unroll
            for (int r = 0; r < 4; ++r)
                sc[nt][r] = (k0 + 16 * nt <= q0 + r) ? Sacc[nt][r] : -INFINITY;

#pragma unroll
        for (int r = 0; r < 4; ++r) {
            float mr = fmaxf(fmaxf(sc[0][r], sc[1][r]), fmaxf(sc[2][r], sc[3][r]));
            mr = fmaxf(mr, __shfl_xor(mr, 1));
            mr = fmaxf(mr, __shfl_xor(mr, 2));
            mr = fmaxf(mr, __shfl_xor(mr, 4));
            mr = fmaxf(mr, __shfl_xor(mr, 8));
            const float mnew = fmaxf(mrow[r], mr);
            const float fac  = __expf(mrow[r] - mnew);   // first tile: exp(-inf)=0
            mrow[r] = mnew;
            float ps = 0.f;
            const int q = g * 4 + r;
#pragma unroll
            for (int nt = 0; nt < 4; ++nt) {
                const float p = __expf(sc[nt][r] - mnew);
                ps += p;
                const uint_t pb = __float_as_uint(p);
                Ph[wid][q][a + 16 * nt] = (ushort_t)(pb >> 16);
                const float phf = __uint_as_float(pb & 0xFFFF0000u);
                Pl[wid][q][a + 16 * nt] = (ushort_t)(__float_as_uint(p - phf) >> 16);
            }
            lrow[r] = lrow[r] * fac + ps;   // per-lane partial; fac row-uniform
#pragma unroll
            for (int nt = 0; nt < 4; ++nt) Oacc[nt][r] *= fac;
        }

        // ---- PV: D[q=(g*4+r)][dh=a+16nt], k-dim = key (same-wave lgkmcnt orders
        // the P writes above before these reads)
#pragma unroll
        for (int kit = 0; kit < 2; ++kit) {
            const u32x4 pah = *(const u32x4*)&Ph[wid][a][kit * 32 + g * 8];
            const u32x4 pal = *(const u32x4*)&Pl[wid][a][kit * 32 + g * 8];
#pragma unroll
            for (int nt = 0; nt < 4; ++nt) {
                const u32x4 vbh = *(const u32x4*)&Vhi[a + 16 * nt][kit * 32 + g * 8];
                const u32x4 vbl = *(const u32x4*)&Vlo[a + 16 * nt][kit * 32 + g * 8];
                Oacc[nt] = MFMA16(pah, vbh, Oacc[nt]);
                Oacc[nt] = MFMA16(pah, vbl, Oacc[nt]);
                Oacc[nt] = MFMA16(pal, vbh, Oacc[nt]);
            }
        }
    }

    // ---- epilogue: row-sum reduce, normalize, store [b][s][h*DH+dh]
    float inv[4];
#pragma unroll
    for (int r = 0; r < 4; ++r) {
        float ls = lrow[r];
        ls += __shfl_xor(ls, 1);
        ls += __shfl_xor(ls, 2);
        ls += __shfl_xor(ls, 4);
        ls += __shfl_xor(ls, 8);
        inv[r] = 1.f / ls;
    }
    const int b = bh >> 3, h = bh & 7;
#pragma unroll
    for (int r = 0; r < 4; ++r) {
        const int qg = qt * 64 + wid * 16 + g * 4 + r;
        float* dst = hidden + ((size_t)b * S_ + qg) * HID_ + h * DH_ + a;
#pragma unroll
        for (int nt = 0; nt < 4; ++nt) dst[16 * nt] = Oacc[nt][r] * inv[r];
    }
}

// ---------------------------------------------------------------------------
// Launch
// ---------------------------------------------------------------------------
extern "C" void kernel_launch(void* const* d_in, const int* in_sizes, int n_in,
                              void* d_out, int out_size, void* d_ws, size_t ws_size,
                              hipStream_t stream)
{
    const float* q  = (const float*)d_in[0];
    const float* k  = (const float*)d_in[1];
    const float* v  = (const float*)d_in[2];
    const float* Wq = (const float*)d_in[3];
    const float* bq = (const float*)d_in[4];
    const float* Wk = (const float*)d_in[5];
    const float* bk = (const float*)d_in[6];
    const float* Wv = (const float*)d_in[7];
    const float* bv = (const float*)d_in[8];
    const float* Wo = (const float*)d_in[9];
    const float* bo = (const float*)d_in[10];
    const float* dq = (const float*)d_in[11];
    const float* dk = (const float*)d_in[12];
    float* out = (float*)d_out;

    float* ws = (float*)d_ws;
    const size_t TEN = (size_t)B_ * S_ * HID_;
    float* qh     = ws;             // [b][h][s][dh]
    float* kh     = ws + TEN;       // [b][h][s][dh]
    float* vtr    = ws + 2 * TEN;   // [b][h][dh][s]  (transposed V heads)
    float* hidden = ws + 3 * TEN;   // [b][s][hid]

    QkvPtrs p;
    p.A[0] = q; p.W[0] = Wq; p.bias[0] = bq; p.out[0] = qh;
    p.A[1] = k; p.W[1] = Wk; p.bias[1] = bk; p.out[1] = kh;
    p.A[2] = v; p.W[2] = Wv; p.bias[2] = bv; p.out[2] = vtr;

    gemm_qkv_kernel<<<dim3(M_ / 64, HID_ / 64, 3), 256, 0, stream>>>(p);
    euler_rot_kernel<<<(2 * B_ * H_ * S_ * (DH_ / 2)) / 256, 256, 0, stream>>>(qh, kh, dq, dk);
    attn_mfma_kernel<<<dim3(S_ / 64, B_ * H_), 256, 0, stream>>>(qh, kh, vtr, hidden);
    gemm_out_kernel<<<dim3(M_ / 64, HID_ / 64), 256, 0, stream>>>(hidden, Wo, bo, out);
}

// Round 3
// 268.654 us; speedup vs baseline: 3.2318x; 1.2317x over previous
//
#include <hip/hip_runtime.h>
#include <math.h>

// Problem constants
constexpr int B_   = 2;
constexpr int S_   = 2048;
constexpr int HID_ = 512;
constexpr int H_   = 8;
constexpr int DH_  = 64;
constexpr int M_   = B_ * S_;

typedef unsigned short ushort_t;
typedef unsigned int   uint_t;
typedef __attribute__((ext_vector_type(4))) float  f32x4;
typedef __attribute__((ext_vector_type(8))) __bf16 bf16x8;
typedef __attribute__((ext_vector_type(4))) uint_t u32x4;

#define MFMA16(A, Bv, C) __builtin_amdgcn_mfma_f32_16x16x32_bf16( \
    __builtin_bit_cast(bf16x8, (A)), __builtin_bit_cast(bf16x8, (Bv)), (C), 0, 0, 0)

// Split fp32 x -> hi bf16 (truncate) + lo bf16 (truncate of exact residual).
// Packs two elements: returns {hi0|hi1<<16, lo0|lo1<<16}.
__device__ __forceinline__ uint2 splitPair(float x0, float x1) {
    uint_t b0 = __float_as_uint(x0), b1 = __float_as_uint(x1);
    uint_t hi = (b0 >> 16) | (b1 & 0xFFFF0000u);
    float h0 = __uint_as_float(b0 & 0xFFFF0000u);
    float h1 = __uint_as_float(b1 & 0xFFFF0000u);
    uint_t l0 = __float_as_uint(x0 - h0), l1 = __float_as_uint(x1 - h1);
    uint_t lo = (l0 >> 16) | (l1 & 0xFFFF0000u);
    return make_uint2(hi, lo);
}

// ---------------------------------------------------------------------------
// Split-bf16 MFMA GEMM: C(M,N) = A(M,K)*W(N,K)^T + bias, M=4096, N=K=512.
// x*y ~= xh*yh + xh*yl + xl*yh (3 MFMAs, rel err ~3e-5), fp32 accum.
// BM=64, BN=128, BK=32; 256 threads = 4 waves (2x2), wave = 32x64 quadrant.
// LDS planes padded to 40 shorts/row (80 B, 16B-aligned; stride 20 words
// spreads 16-lane frag reads across banks).
// MODE 0: out[m][n]; MODE 1: [b][h][s][d]; MODE 2: [b][h][d][s] (V^T).
// ---------------------------------------------------------------------------
template <int MODE>
__device__ __forceinline__ void gemm_mfma_body(const float* __restrict__ A,
                                               const float* __restrict__ W,
                                               const float* __restrict__ bias,
                                               float* __restrict__ out)
{
    constexpr int K_ = HID_;
    __shared__ __align__(16) ushort_t Ah[64][40],  Al[64][40];
    __shared__ __align__(16) ushort_t Bh[128][40], Bl[128][40];

    const int t    = threadIdx.x;
    const int lane = t & 63;
    const int wid  = t >> 6;
    const int wr   = wid >> 1;      // 0..1  (row quadrant, 32 rows)
    const int wc   = wid & 1;       // 0..1  (col quadrant, 64 cols)
    const int a    = lane & 15;
    const int g    = lane >> 4;
    const int bm   = blockIdx.x * 64;
    const int bn   = blockIdx.y * 128;

    f32x4 acc[2][4];
#pragma unroll
    for (int mt = 0; mt < 2; ++mt)
#pragma unroll
        for (int nt = 0; nt < 4; ++nt)
#pragma unroll
            for (int r = 0; r < 4; ++r) acc[mt][nt][r] = 0.f;

    // staging indices (A: 256 segs of 8; B: 512 segs of 8)
    const int arow = t >> 2, ag8 = t & 3;

    for (int k0 = 0; k0 < K_; k0 += 32) {
        __syncthreads();
        // ---- stage A tile (64x32 fp32 -> split bf16)
        {
            const float* p = A + (size_t)(bm + arow) * K_ + k0 + ag8 * 8;
            const float4 x0 = *(const float4*)p;
            const float4 x1 = *(const float4*)(p + 4);
            const uint2 s0 = splitPair(x0.x, x0.y), s1 = splitPair(x0.z, x0.w);
            const uint2 s2 = splitPair(x1.x, x1.y), s3 = splitPair(x1.z, x1.w);
            *(u32x4*)&Ah[arow][ag8 * 8] = u32x4{s0.x, s1.x, s2.x, s3.x};
            *(u32x4*)&Al[arow][ag8 * 8] = u32x4{s0.y, s1.y, s2.y, s3.y};
        }
        // ---- stage B tile (128x32)
#pragma unroll
        for (int i = 0; i < 2; ++i) {
            const int seg = t + i * 256;
            const int row = seg >> 2, g8 = seg & 3;
            const float* p = W + (size_t)(bn + row) * K_ + k0 + g8 * 8;
            const float4 x0 = *(const float4*)p;
            const float4 x1 = *(const float4*)(p + 4);
            const uint2 s0 = splitPair(x0.x, x0.y), s1 = splitPair(x0.z, x0.w);
            const uint2 s2 = splitPair(x1.x, x1.y), s3 = splitPair(x1.z, x1.w);
            *(u32x4*)&Bh[row][g8 * 8] = u32x4{s0.x, s1.x, s2.x, s3.x};
            *(u32x4*)&Bl[row][g8 * 8] = u32x4{s0.y, s1.y, s2.y, s3.y};
        }
        __syncthreads();

        // ---- fragments + MFMA
        u32x4 afh[2], afl[2];
#pragma unroll
        for (int mt = 0; mt < 2; ++mt) {
            const int ar = wr * 32 + mt * 16 + a;
            afh[mt] = *(const u32x4*)&Ah[ar][g * 8];
            afl[mt] = *(const u32x4*)&Al[ar][g * 8];
        }
#pragma unroll
        for (int nt = 0; nt < 4; ++nt) {
            const int br = wc * 64 + nt * 16 + a;
            const u32x4 bfh = *(const u32x4*)&Bh[br][g * 8];
            const u32x4 bfl = *(const u32x4*)&Bl[br][g * 8];
#pragma unroll
            for (int mt = 0; mt < 2; ++mt) {
                acc[mt][nt] = MFMA16(afh[mt], bfh, acc[mt][nt]);
                acc[mt][nt] = MFMA16(afh[mt], bfl, acc[mt][nt]);
                acc[mt][nt] = MFMA16(afl[mt], bfh, acc[mt][nt]);
            }
        }
    }

    // ---- epilogue: bias + store (D: row = g*4+r, col = a)
#pragma unroll
    for (int mt = 0; mt < 2; ++mt) {
#pragma unroll
        for (int nt = 0; nt < 4; ++nt) {
            const int n = bn + wc * 64 + nt * 16 + a;
            const float bb = bias[n];
#pragma unroll
            for (int r = 0; r < 4; ++r) {
                const int m = bm + wr * 32 + mt * 16 + g * 4 + r;
                const float val = acc[mt][nt][r] + bb;
                if (MODE == 0) {
                    out[(size_t)m * HID_ + n] = val;
                } else {
                    const int b = m >> 11;
                    const int s = m & (S_ - 1);
                    const int h = n >> 6;
                    const int d = n & (DH_ - 1);
                    if (MODE == 1)
                        out[(((size_t)b * H_ + h) * S_ + s) * DH_ + d] = val;
                    else
                        out[(((size_t)b * H_ + h) * DH_ + d) * S_ + s] = val;
                }
            }
        }
    }
}

struct QkvPtrs {
    const float* A[3];
    const float* W[3];
    const float* bias[3];
    float*       out[3];
};

__global__ __launch_bounds__(256)
void gemm_qkv_kernel(QkvPtrs p)
{
    const int z = blockIdx.z;   // 0=q 1=k 2=v
    if (z == 2) gemm_mfma_body<2>(p.A[2], p.W[2], p.bias[2], p.out[2]);
    else        gemm_mfma_body<1>(p.A[z], p.W[z], p.bias[z], p.out[z]);
}

__global__ __launch_bounds__(256)
void gemm_out_kernel(const float* __restrict__ A, const float* __restrict__ W,
                     const float* __restrict__ bias, float* __restrict__ out)
{
    gemm_mfma_body<0>(A, W, bias, out);
}

// ---------------------------------------------------------------------------
// Euler rotation, in-place on q/k head tensors ([b][h][s][dh]). Unchanged.
// ---------------------------------------------------------------------------
__global__ __launch_bounds__(256)
void euler_rot_kernel(float* __restrict__ qh, float* __restrict__ kh,
                      const float* __restrict__ dq, const float* __restrict__ dk)
{
    constexpr int NP = B_ * H_ * S_ * (DH_ / 2);
    const int idx = blockIdx.x * 256 + threadIdx.x;

    float* x; float delta; int pi;
    if (idx < NP) { x = qh; delta = dq[0]; pi = idx; }
    else          { x = kh; delta = dk[0]; pi = idx - NP; }

    const int i = pi & 31;
    const int s = (pi >> 5) & (S_ - 1);
    const float freq = exp2f(-(float)i * 0.4152410118609203f);  // 10000^(-i/32)

    const float2 rp = ((const float2*)x)[pi];
    const float lam = sqrtf(rp.x * rp.x + rp.y * rp.y);
    const float th  = atan2f(rp.y, rp.x) * delta + (float)s * freq;
    float sn, cs;
    sincosf(th, &sn, &cs);
    ((float2*)x)[pi] = make_float2(lam * cs, lam * sn);
}

// ---------------------------------------------------------------------------
// Flash attention (causal), split-bf16 MFMA (16x16x32), fp32 softmax.
// Grid (32, B*H), block 256 = 4 waves. Wave w owns q-rows [qt*64+w*16, +16).
// (unchanged from round 2)
// ---------------------------------------------------------------------------
__global__ __launch_bounds__(256)
void attn_mfma_kernel(const float* __restrict__ qh, const float* __restrict__ kh,
                      const float* __restrict__ vt, float* __restrict__ hidden)
{
    __shared__ __align__(16) ushort_t Khi[64][72];
    __shared__ __align__(16) ushort_t Klo[64][72];
    __shared__ __align__(16) ushort_t Vhi[64][72];   // [dh][key]
    __shared__ __align__(16) ushort_t Vlo[64][72];
    __shared__ __align__(16) ushort_t Ph[4][16][72]; // per-wave [q][key]
    __shared__ __align__(16) ushort_t Pl[4][16][72];

    const int t    = threadIdx.x;
    const int lane = t & 63;
    const int wid  = t >> 6;
    const int a    = lane & 15;
    const int g    = lane >> 4;
    const int qt   = 31 - blockIdx.x;   // heavy tiles first (LPT)
    const int bh   = blockIdx.y;

    const float* Qrow = qh + ((size_t)bh * S_ + (size_t)qt * 64 + wid * 16 + a) * DH_;
    u32x4 qhi[2], qlo[2];
#pragma unroll
    for (int kit = 0; kit < 2; ++kit) {
        const float* p = Qrow + kit * 32 + g * 8;
        const float4 x0 = *(const float4*)p;
        const float4 x1 = *(const float4*)(p + 4);
        const uint2 p0 = splitPair(x0.x * 0.125f, x0.y * 0.125f);
        const uint2 p1 = splitPair(x0.z * 0.125f, x0.w * 0.125f);
        const uint2 p2 = splitPair(x1.x * 0.125f, x1.y * 0.125f);
        const uint2 p3 = splitPair(x1.z * 0.125f, x1.w * 0.125f);
        qhi[kit] = u32x4{p0.x, p1.x, p2.x, p3.x};
        qlo[kit] = u32x4{p0.y, p1.y, p2.y, p3.y};
    }

    f32x4 Oacc[4];
#pragma unroll
    for (int nt = 0; nt < 4; ++nt)
#pragma unroll
        for (int r = 0; r < 4; ++r) Oacc[nt][r] = 0.f;
    float mrow[4] = {-INFINITY, -INFINITY, -INFINITY, -INFINITY};
    float lrow[4] = {0.f, 0.f, 0.f, 0.f};

    const float4* Kg = (const float4*)(kh + (size_t)bh * S_ * DH_);  // [key][dh]
    const float*  Vg = vt + (size_t)bh * DH_ * S_;                   // [dh][s]

    for (int kt = 0; kt <= qt; ++kt) {
        __syncthreads();
#pragma unroll
        for (int i = 0; i < 4; ++i) {
            const int flat = t + i * 256;
            const int key = flat >> 4, d4 = (flat & 15) * 4;
            const float4 kv = Kg[kt * 1024 + flat];
            const uint2 s01 = splitPair(kv.x, kv.y);
            const uint2 s23 = splitPair(kv.z, kv.w);
            *(uint2*)&Khi[key][d4] = make_uint2(s01.x, s23.x);
            *(uint2*)&Klo[key][d4] = make_uint2(s01.y, s23.y);
        }
#pragma unroll
        for (int i = 0; i < 4; ++i) {
            const int flat = t + i * 256;
            const int dh = flat >> 4, k4 = (flat & 15) * 4;
            const float4 vv = *(const float4*)(Vg + (size_t)dh * S_ + kt * 64 + k4);
            const uint2 s01 = splitPair(vv.x, vv.y);
            const uint2 s23 = splitPair(vv.z, vv.w);
            *(uint2*)&Vhi[dh][k4] = make_uint2(s01.x, s23.x);
            *(uint2*)&Vlo[dh][k4] = make_uint2(s01.y, s23.y);
        }
        __syncthreads();

        f32x4 Sacc[4];
#pragma unroll
        for (int nt = 0; nt < 4; ++nt)
#pragma unroll
            for (int r = 0; r < 4; ++r) Sacc[nt][r] = 0.f;
#pragma unroll
        for (int kit = 0; kit < 2; ++kit) {
#pragma unroll
            for (int nt = 0; nt < 4; ++nt) {
                const u32x4 kbh = *(const u32x4*)&Khi[a + 16 * nt][kit * 32 + g * 8];
                const u32x4 kbl = *(const u32x4*)&Klo[a + 16 * nt][kit * 32 + g * 8];
                Sacc[nt] = MFMA16(qhi[kit], kbh, Sacc[nt]);
                Sacc[nt] = MFMA16(qhi[kit], kbl, Sacc[nt]);
                Sacc[nt] = MFMA16(qlo[kit], kbh, Sacc[nt]);
            }
        }

        float sc[4][4];
        const int q0 = qt * 64 + wid * 16 + g * 4;
        const int k0 = kt * 64 + a;
#pragma unroll
        for (int nt = 0; nt < 4; ++nt)
#pragma unroll
            for (int r = 0; r < 4; ++r)
                sc[nt][r] = (k0 + 16 * nt <= q0 + r) ? Sacc[nt][r] : -INFINITY;

#pragma unroll
        for (int r = 0; r < 4; ++r) {
            float mr = fmaxf(fmaxf(sc[0][r], sc[1][r]), fmaxf(sc[2][r], sc[3][r]));
            mr = fmaxf(mr, __shfl_xor(mr, 1));
            mr = fmaxf(mr, __shfl_xor(mr, 2));
            mr = fmaxf(mr, __shfl_xor(mr, 4));
            mr = fmaxf(mr, __shfl_xor(mr, 8));
            const float mnew = fmaxf(mrow[r], mr);
            const float fac  = __expf(mrow[r] - mnew);
            mrow[r] = mnew;
            float ps = 0.f;
            const int q = g * 4 + r;
#pragma unroll
            for (int nt = 0; nt < 4; ++nt) {
                const float p = __expf(sc[nt][r] - mnew);
                ps += p;
                const uint_t pb = __float_as_uint(p);
                Ph[wid][q][a + 16 * nt] = (ushort_t)(pb >> 16);
                const float phf = __uint_as_float(pb & 0xFFFF0000u);
                Pl[wid][q][a + 16 * nt] = (ushort_t)(__float_as_uint(p - phf) >> 16);
            }
            lrow[r] = lrow[r] * fac + ps;
#pragma unroll
            for (int nt = 0; nt < 4; ++nt) Oacc[nt][r] *= fac;
        }

#pragma unroll
        for (int kit = 0; kit < 2; ++kit) {
            const u32x4 pah = *(const u32x4*)&Ph[wid][a][kit * 32 + g * 8];
            const u32x4 pal = *(const u32x4*)&Pl[wid][a][kit * 32 + g * 8];
#pragma unroll
            for (int nt = 0; nt < 4; ++nt) {
                const u32x4 vbh = *(const u32x4*)&Vhi[a + 16 * nt][kit * 32 + g * 8];
                const u32x4 vbl = *(const u32x4*)&Vlo[a + 16 * nt][kit * 32 + g * 8];
                Oacc[nt] = MFMA16(pah, vbh, Oacc[nt]);
                Oacc[nt] = MFMA16(pah, vbl, Oacc[nt]);
                Oacc[nt] = MFMA16(pal, vbh, Oacc[nt]);
            }
        }
    }

    float inv[4];
#pragma unroll
    for (int r = 0; r < 4; ++r) {
        float ls = lrow[r];
        ls += __shfl_xor(ls, 1);
        ls += __shfl_xor(ls, 2);
        ls += __shfl_xor(ls, 4);
        ls += __shfl_xor(ls, 8);
        inv[r] = 1.f / ls;
    }
    const int b = bh >> 3, h = bh & 7;
#pragma unroll
    for (int r = 0; r < 4; ++r) {
        const int qg = qt * 64 + wid * 16 + g * 4 + r;
        float* dst = hidden + ((size_t)b * S_ + qg) * HID_ + h * DH_ + a;
#pragma unroll
        for (int nt = 0; nt < 4; ++nt) dst[16 * nt] = Oacc[nt][r] * inv[r];
    }
}

// ---------------------------------------------------------------------------
// Launch
// ---------------------------------------------------------------------------
extern "C" void kernel_launch(void* const* d_in, const int* in_sizes, int n_in,
                              void* d_out, int out_size, void* d_ws, size_t ws_size,
                              hipStream_t stream)
{
    const float* q  = (const float*)d_in[0];
    const float* k  = (const float*)d_in[1];
    const float* v  = (const float*)d_in[2];
    const float* Wq = (const float*)d_in[3];
    const float* bq = (const float*)d_in[4];
    const float* Wk = (const float*)d_in[5];
    const float* bk = (const float*)d_in[6];
    const float* Wv = (const float*)d_in[7];
    const float* bv = (const float*)d_in[8];
    const float* Wo = (const float*)d_in[9];
    const float* bo = (const float*)d_in[10];
    const float* dq = (const float*)d_in[11];
    const float* dk = (const float*)d_in[12];
    float* out = (float*)d_out;

    float* ws = (float*)d_ws;
    const size_t TEN = (size_t)B_ * S_ * HID_;
    float* qh     = ws;             // [b][h][s][dh]
    float* kh     = ws + TEN;       // [b][h][s][dh]
    float* vtr    = ws + 2 * TEN;   // [b][h][dh][s]
    float* hidden = ws + 3 * TEN;   // [b][s][hid]

    QkvPtrs p;
    p.A[0] = q; p.W[0] = Wq; p.bias[0] = bq; p.out[0] = qh;
    p.A[1] = k; p.W[1] = Wk; p.bias[1] = bk; p.out[1] = kh;
    p.A[2] = v; p.W[2] = Wv; p.bias[2] = bv; p.out[2] = vtr;

    gemm_qkv_kernel<<<dim3(M_ / 64, HID_ / 128, 3), 256, 0, stream>>>(p);
    euler_rot_kernel<<<(2 * B_ * H_ * S_ * (DH_ / 2)) / 256, 256, 0, stream>>>(qh, kh, dq, dk);
    attn_mfma_kernel<<<dim3(S_ / 64, B_ * H_), 256, 0, stream>>>(qh, kh, vtr, hidden);
    gemm_out_kernel<<<dim3(M_ / 64, HID_ / 128), 256, 0, stream>>>(hidden, Wo, bo, out);
}

// Round 5
// 243.027 us; speedup vs baseline: 3.5726x; 1.1055x over previous
//
#include <hip/hip_runtime.h>
#include <math.h>

// Problem constants
constexpr int B_   = 2;
constexpr int S_   = 2048;
constexpr int HID_ = 512;
constexpr int H_   = 8;
constexpr int DH_  = 64;
constexpr int M_   = B_ * S_;

typedef unsigned short ushort_t;
typedef unsigned int   uint_t;
typedef __attribute__((ext_vector_type(4))) float  f32x4;
typedef __attribute__((ext_vector_type(8))) __bf16 bf16x8;
typedef __attribute__((ext_vector_type(4))) uint_t u32x4;

#define MFMA16(A, Bv, C) __builtin_amdgcn_mfma_f32_16x16x32_bf16( \
    __builtin_bit_cast(bf16x8, (A)), __builtin_bit_cast(bf16x8, (Bv)), (C), 0, 0, 0)

// Split fp32 x -> hi bf16 (truncate) + lo bf16 (truncate of exact residual).
// Packs two elements: returns {hi0|hi1<<16, lo0|lo1<<16}.
__device__ __forceinline__ uint2 splitPair(float x0, float x1) {
    uint_t b0 = __float_as_uint(x0), b1 = __float_as_uint(x1);
    uint_t hi = (b0 >> 16) | (b1 & 0xFFFF0000u);
    float h0 = __uint_as_float(b0 & 0xFFFF0000u);
    float h1 = __uint_as_float(b1 & 0xFFFF0000u);
    uint_t l0 = __float_as_uint(x0 - h0), l1 = __float_as_uint(x1 - h1);
    uint_t lo = (l0 >> 16) | (l1 & 0xFFFF0000u);
    return make_uint2(hi, lo);
}

__device__ __forceinline__ void splitOne(float x, ushort_t& hi, ushort_t& lo) {
    uint_t b = __float_as_uint(x);
    hi = (ushort_t)(b >> 16);
    float h = __uint_as_float(b & 0xFFFF0000u);
    lo = (ushort_t)(__float_as_uint(x - h) >> 16);
}

// ---------------------------------------------------------------------------
// Split-bf16 MFMA GEMM with register-prefetch pipeline.
// C(M,N) = A(M,K)*W(N,K)^T + bias; M=4096, N=K=512.
// BM=BN=64, BK=32; 256 thr = 4 waves (2x2), wave = 32x32 (mt,nt = 2x2).
// MODE 0: fp32 out[m][n]
// MODE 1: Q — euler(delta)+scale(1/8) -> split planes [b][h][s][d]
// MODE 2: K — euler(delta)           -> split planes [b][h][s][d]
// MODE 3: V —                         -> split planes [b][h][d][s] (V^T)
// ---------------------------------------------------------------------------
template <int MODE>
__device__ __forceinline__ void gemm_mfma_body(const float* __restrict__ A,
                                               const float* __restrict__ W,
                                               const float* __restrict__ bias,
                                               ushort_t* __restrict__ outHi,
                                               ushort_t* __restrict__ outLo,
                                               float* __restrict__ outF,
                                               const float* __restrict__ delta)
{
    constexpr int K_ = HID_;
    __shared__ __align__(16) ushort_t Ah[64][40], Al[64][40];
    __shared__ __align__(16) ushort_t Bh[64][40], Bl[64][40];

    const int t    = threadIdx.x;
    const int lane = t & 63;
    const int wid  = t >> 6;
    const int wr   = wid >> 1;
    const int wc   = wid & 1;
    const int a    = lane & 15;
    const int g    = lane >> 4;
    const int bm   = blockIdx.x * 64;
    const int bn   = blockIdx.y * 64;

    // staging: tile 64x32 = 2048 fp32, 256 thr x 8; row = t>>2, col8 = (t&3)*8
    const int srow = t >> 2, sg8 = t & 3;
    const float* Ap = A + (size_t)(bm + srow) * K_ + sg8 * 8;
    const float* Wp = W + (size_t)(bn + srow) * K_ + sg8 * 8;

    float4 ra0 = *(const float4*)Ap,       ra1 = *(const float4*)(Ap + 4);
    float4 rb0 = *(const float4*)Wp,       rb1 = *(const float4*)(Wp + 4);

    f32x4 acc[2][2];
#pragma unroll
    for (int mt = 0; mt < 2; ++mt)
#pragma unroll
        for (int nt = 0; nt < 2; ++nt)
#pragma unroll
            for (int r = 0; r < 4; ++r) acc[mt][nt][r] = 0.f;

    for (int k0 = 0; k0 < K_; k0 += 32) {
        __syncthreads();   // previous iter done reading LDS
        {
            const uint2 s0 = splitPair(ra0.x, ra0.y), s1 = splitPair(ra0.z, ra0.w);
            const uint2 s2 = splitPair(ra1.x, ra1.y), s3 = splitPair(ra1.z, ra1.w);
            *(u32x4*)&Ah[srow][sg8 * 8] = u32x4{s0.x, s1.x, s2.x, s3.x};
            *(u32x4*)&Al[srow][sg8 * 8] = u32x4{s0.y, s1.y, s2.y, s3.y};
            const uint2 t0 = splitPair(rb0.x, rb0.y), t1 = splitPair(rb0.z, rb0.w);
            const uint2 t2 = splitPair(rb1.x, rb1.y), t3 = splitPair(rb1.z, rb1.w);
            *(u32x4*)&Bh[srow][sg8 * 8] = u32x4{t0.x, t1.x, t2.x, t3.x};
            *(u32x4*)&Bl[srow][sg8 * 8] = u32x4{t0.y, t1.y, t2.y, t3.y};
        }
        if (k0 + 32 < K_) {    // prefetch next tile into regs (hides latency)
            const float* pa = Ap + k0 + 32;
            const float* pw = Wp + k0 + 32;
            ra0 = *(const float4*)pa; ra1 = *(const float4*)(pa + 4);
            rb0 = *(const float4*)pw; rb1 = *(const float4*)(pw + 4);
        }
        __syncthreads();

        u32x4 afh[2], afl[2], bfh[2], bfl[2];
#pragma unroll
        for (int mt = 0; mt < 2; ++mt) {
            const int ar = wr * 32 + mt * 16 + a;
            afh[mt] = *(const u32x4*)&Ah[ar][g * 8];
            afl[mt] = *(const u32x4*)&Al[ar][g * 8];
        }
#pragma unroll
        for (int nt = 0; nt < 2; ++nt) {
            const int br = wc * 32 + nt * 16 + a;
            bfh[nt] = *(const u32x4*)&Bh[br][g * 8];
            bfl[nt] = *(const u32x4*)&Bl[br][g * 8];
        }
#pragma unroll
        for (int nt = 0; nt < 2; ++nt)
#pragma unroll
            for (int mt = 0; mt < 2; ++mt) {
                acc[mt][nt] = MFMA16(afh[mt], bfh[nt], acc[mt][nt]);
                acc[mt][nt] = MFMA16(afh[mt], bfl[nt], acc[mt][nt]);
                acc[mt][nt] = MFMA16(afl[mt], bfh[nt], acc[mt][nt]);
            }
    }

    // ---- epilogue (D: row = g*4+r, col = a within each 16x16)
    const float del = (MODE == 1 || MODE == 2) ? delta[0] : 0.f;
#pragma unroll
    for (int mt = 0; mt < 2; ++mt) {
#pragma unroll
        for (int nt = 0; nt < 2; ++nt) {
            const int n  = bn + wc * 32 + nt * 16 + a;
            const float bb = bias[n];
            f32x4 vals;
#pragma unroll
            for (int r = 0; r < 4; ++r) vals[r] = acc[mt][nt][r] + bb;

            if (MODE == 0) {
#pragma unroll
                for (int r = 0; r < 4; ++r) {
                    const int m = bm + wr * 32 + mt * 16 + g * 4 + r;
                    outF[(size_t)m * HID_ + n] = vals[r];
                }
            } else if (MODE == 1 || MODE == 2) {
                const int d  = n & 63;
                const int h  = n >> 6;
                const float freq = exp2f(-(float)(d >> 1) * 0.4152410118609203f);
#pragma unroll
                for (int r = 0; r < 4; ++r) {
                    const int m = bm + wr * 32 + mt * 16 + g * 4 + r;
                    const int b = m >> 11, s = m & (S_ - 1);
                    const float val  = vals[r];
                    const float part = __shfl_xor(val, 1);
                    const float rr = (a & 1) ? part : val;
                    const float pp = (a & 1) ? val  : part;
                    const float lam = sqrtf(rr * rr + pp * pp);
                    const float th  = atan2f(pp, rr) * del + (float)s * freq;
                    float sn, cs;
                    sincosf(th, &sn, &cs);
                    float o = (a & 1) ? lam * sn : lam * cs;
                    if (MODE == 1) o *= 0.125f;   // 1/sqrt(DH) pre-applied to Q
                    ushort_t hi, lo;
                    splitOne(o, hi, lo);
                    const size_t idx = (((size_t)b * H_ + h) * S_ + s) * DH_ + d;
                    outHi[idx] = hi;
                    outLo[idx] = lo;
                }
            } else {   // MODE 3: V^T planes [b][h][d][s], r-dim = 4 consecutive s
                const int d  = n & 63;
                const int h  = n >> 6;
                const int m0 = bm + wr * 32 + mt * 16 + g * 4;
                const int b  = m0 >> 11, s0 = m0 & (S_ - 1);
                const uint2 p01 = splitPair(vals[0], vals[1]);
                const uint2 p23 = splitPair(vals[2], vals[3]);
                const size_t idx = (((size_t)b * H_ + h) * DH_ + d) * S_ + s0;
                *(uint2*)&outHi[idx] = make_uint2(p01.x, p23.x);
                *(uint2*)&outLo[idx] = make_uint2(p01.y, p23.y);
            }
        }
    }
}

struct QkvPtrs {
    const float* A[3];
    const float* W[3];
    const float* bias[3];
    ushort_t*    hi[3];
    ushort_t*    lo[3];
    const float* del[2];
};

__global__ __launch_bounds__(256)
void gemm_qkv_kernel(QkvPtrs p)
{
    const int z = blockIdx.z;   // 0=q 1=k 2=v
    if (z == 0)      gemm_mfma_body<1>(p.A[0], p.W[0], p.bias[0], p.hi[0], p.lo[0], nullptr, p.del[0]);
    else if (z == 1) gemm_mfma_body<2>(p.A[1], p.W[1], p.bias[1], p.hi[1], p.lo[1], nullptr, p.del[1]);
    else             gemm_mfma_body<3>(p.A[2], p.W[2], p.bias[2], p.hi[2], p.lo[2], nullptr, nullptr);
}

__global__ __launch_bounds__(256)
void gemm_out_kernel(const float* __restrict__ A, const float* __restrict__ W,
                     const float* __restrict__ bias, float* __restrict__ out)
{
    gemm_mfma_body<0>(A, W, bias, nullptr, nullptr, out, nullptr);
}

// ---------------------------------------------------------------------------
// Flash attention (causal), split-bf16 MFMA (16x16x32), fp32 softmax.
// Inputs are pre-split bf16 hi/lo planes: Q/K [b][h][s][d], V [b][h][d][s].
// Q pre-scaled by 1/sqrt(DH). Staging = pure 16B copies. Grid (32, B*H),
// block 256 = 4 waves; wave w owns q-rows [qt*64+w*16, +16).
// ---------------------------------------------------------------------------
__global__ __launch_bounds__(256)
void attn_mfma_kernel(const ushort_t* __restrict__ qhi_g, const ushort_t* __restrict__ qlo_g,
                      const ushort_t* __restrict__ khi_g, const ushort_t* __restrict__ klo_g,
                      const ushort_t* __restrict__ vhi_g, const ushort_t* __restrict__ vlo_g,
                      float* __restrict__ hidden)
{
    __shared__ __align__(16) ushort_t Khi[64][72];
    __shared__ __align__(16) ushort_t Klo[64][72];
    __shared__ __align__(16) ushort_t Vhi[64][72];   // [dh][key]
    __shared__ __align__(16) ushort_t Vlo[64][72];
    __shared__ __align__(16) ushort_t Ph[4][16][72]; // per-wave [q][key]
    __shared__ __align__(16) ushort_t Pl[4][16][72];

    const int t    = threadIdx.x;
    const int lane = t & 63;
    const int wid  = t >> 6;
    const int a    = lane & 15;
    const int g    = lane >> 4;
    const int qt   = 31 - blockIdx.x;   // heavy tiles first (LPT)
    const int bh   = blockIdx.y;

    // Q fragments straight from split planes (pre-scaled)
    u32x4 qhi[2], qlo[2];
    {
        const size_t qrow = ((size_t)bh * S_ + (size_t)qt * 64 + wid * 16 + a) * DH_;
#pragma unroll
        for (int kit = 0; kit < 2; ++kit) {
            qhi[kit] = *(const u32x4*)&qhi_g[qrow + kit * 32 + g * 8];
            qlo[kit] = *(const u32x4*)&qlo_g[qrow + kit * 32 + g * 8];
        }
    }

    f32x4 Oacc[4];
#pragma unroll
    for (int nt = 0; nt < 4; ++nt)
#pragma unroll
        for (int r = 0; r < 4; ++r) Oacc[nt][r] = 0.f;
    float mrow[4] = {-INFINITY, -INFINITY, -INFINITY, -INFINITY};
    float lrow[4] = {0.f, 0.f, 0.f, 0.f};

    for (int kt = 0; kt <= qt; ++kt) {
        const ushort_t* Ksh = khi_g + ((size_t)bh * S_ + kt * 64) * DH_;
        const ushort_t* Ksl = klo_g + ((size_t)bh * S_ + kt * 64) * DH_;
        const ushort_t* Vsh = vhi_g + (size_t)bh * DH_ * S_ + kt * 64;
        const ushort_t* Vsl = vlo_g + (size_t)bh * DH_ * S_ + kt * 64;
        __syncthreads();
#pragma unroll
        for (int i = 0; i < 2; ++i) {
            const int seg = t + i * 256;        // 512 segs = 64 rows x 8
            const int row = seg >> 3, c8 = (seg & 7) * 8;
            *(u32x4*)&Khi[row][c8] = *(const u32x4*)&Ksh[row * 64 + c8];
            *(u32x4*)&Klo[row][c8] = *(const u32x4*)&Ksl[row * 64 + c8];
            *(u32x4*)&Vhi[row][c8] = *(const u32x4*)&Vsh[(size_t)row * S_ + c8];
            *(u32x4*)&Vlo[row][c8] = *(const u32x4*)&Vsl[(size_t)row * S_ + c8];
        }
        __syncthreads();

        // ---- QK^T: D[q=(g*4+r)][key=a+16nt]
        f32x4 Sacc[4];
#pragma unroll
        for (int nt = 0; nt < 4; ++nt)
#pragma unroll
            for (int r = 0; r < 4; ++r) Sacc[nt][r] = 0.f;
#pragma unroll
        for (int kit = 0; kit < 2; ++kit) {
#pragma unroll
            for (int nt = 0; nt < 4; ++nt) {
                const u32x4 kbh = *(const u32x4*)&Khi[a + 16 * nt][kit * 32 + g * 8];
                const u32x4 kbl = *(const u32x4*)&Klo[a + 16 * nt][kit * 32 + g * 8];
                Sacc[nt] = MFMA16(qhi[kit], kbh, Sacc[nt]);
                Sacc[nt] = MFMA16(qhi[kit], kbl, Sacc[nt]);
                Sacc[nt] = MFMA16(qlo[kit], kbh, Sacc[nt]);
            }
        }

        // ---- causal mask + online softmax
        float sc[4][4];
        const int q0 = qt * 64 + wid * 16 + g * 4;
        const int k0 = kt * 64 + a;
#pragma unroll
        for (int nt = 0; nt < 4; ++nt)
#pragma unroll
            for (int r = 0; r < 4; ++r)
                sc[nt][r] = (k0 + 16 * nt <= q0 + r) ? Sacc[nt][r] : -INFINITY;

#pragma unroll
        for (int r = 0; r < 4; ++r) {
            float mr = fmaxf(fmaxf(sc[0][r], sc[1][r]), fmaxf(sc[2][r], sc[3][r]));
            mr = fmaxf(mr, __shfl_xor(mr, 1));
            mr = fmaxf(mr, __shfl_xor(mr, 2));
            mr = fmaxf(mr, __shfl_xor(mr, 4));
            mr = fmaxf(mr, __shfl_xor(mr, 8));
            const float mnew = fmaxf(mrow[r], mr);
            const float fac  = __expf(mrow[r] - mnew);
            mrow[r] = mnew;
            float ps = 0.f;
            const int q = g * 4 + r;
#pragma unroll
            for (int nt = 0; nt < 4; ++nt) {
                const float p = __expf(sc[nt][r] - mnew);
                ps += p;
                ushort_t phi, plo;
                splitOne(p, phi, plo);
                Ph[wid][q][a + 16 * nt] = phi;
                Pl[wid][q][a + 16 * nt] = plo;
            }
            lrow[r] = lrow[r] * fac + ps;
#pragma unroll
            for (int nt = 0; nt < 4; ++nt) Oacc[nt][r] *= fac;
        }

        // ---- PV: D[q][dh=a+16nt]
#pragma unroll
        for (int kit = 0; kit < 2; ++kit) {
            const u32x4 pah = *(const u32x4*)&Ph[wid][a][kit * 32 + g * 8];
            const u32x4 pal = *(const u32x4*)&Pl[wid][a][kit * 32 + g * 8];
#pragma unroll
            for (int nt = 0; nt < 4; ++nt) {
                const u32x4 vbh = *(const u32x4*)&Vhi[a + 16 * nt][kit * 32 + g * 8];
                const u32x4 vbl = *(const u32x4*)&Vlo[a + 16 * nt][kit * 32 + g * 8];
                Oacc[nt] = MFMA16(pah, vbh, Oacc[nt]);
                Oacc[nt] = MFMA16(pah, vbl, Oacc[nt]);
                Oacc[nt] = MFMA16(pal, vbh, Oacc[nt]);
            }
        }
    }

    // ---- epilogue
    float inv[4];
#pragma unroll
    for (int r = 0; r < 4; ++r) {
        float ls = lrow[r];
        ls += __shfl_xor(ls, 1);
        ls += __shfl_xor(ls, 2);
        ls += __shfl_xor(ls, 4);
        ls += __shfl_xor(ls, 8);
        inv[r] = 1.f / ls;
    }
    const int b = bh >> 3, h = bh & 7;
#pragma unroll
    for (int r = 0; r < 4; ++r) {
        const int qg = qt * 64 + wid * 16 + g * 4 + r;
        float* dst = hidden + ((size_t)b * S_ + qg) * HID_ + h * DH_ + a;
#pragma unroll
        for (int nt = 0; nt < 4; ++nt) dst[16 * nt] = Oacc[nt][r] * inv[r];
    }
}

// ---------------------------------------------------------------------------
// Launch
// ---------------------------------------------------------------------------
extern "C" void kernel_launch(void* const* d_in, const int* in_sizes, int n_in,
                              void* d_out, int out_size, void* d_ws, size_t ws_size,
                              hipStream_t stream)
{
    const float* q  = (const float*)d_in[0];
    const float* k  = (const float*)d_in[1];
    const float* v  = (const float*)d_in[2];
    const float* Wq = (const float*)d_in[3];
    const float* bq = (const float*)d_in[4];
    const float* Wk = (const float*)d_in[5];
    const float* bk = (const float*)d_in[6];
    const float* Wv = (const float*)d_in[7];
    const float* bv = (const float*)d_in[8];
    const float* Wo = (const float*)d_in[9];
    const float* bo = (const float*)d_in[10];
    const float* dq = (const float*)d_in[11];
    const float* dk = (const float*)d_in[12];
    float* out = (float*)d_out;

    // ws (32 MB): 6 ushort planes of TEN + fp32 hidden of TEN
    const size_t TEN = (size_t)B_ * S_ * HID_;   // 2,097,152
    ushort_t* qhi = (ushort_t*)d_ws;
    ushort_t* qlo = qhi + TEN;
    ushort_t* khi = qlo + TEN;
    ushort_t* klo = khi + TEN;
    ushort_t* vhi = klo + TEN;
    ushort_t* vlo = vhi + TEN;
    float* hidden = (float*)(vlo + TEN);

    QkvPtrs p;
    p.A[0] = q; p.W[0] = Wq; p.bias[0] = bq; p.hi[0] = qhi; p.lo[0] = qlo;
    p.A[1] = k; p.W[1] = Wk; p.bias[1] = bk; p.hi[1] = khi; p.lo[1] = klo;
    p.A[2] = v; p.W[2] = Wv; p.bias[2] = bv; p.hi[2] = vhi; p.lo[2] = vlo;
    p.del[0] = dq; p.del[1] = dk;

    gemm_qkv_kernel<<<dim3(M_ / 64, HID_ / 64, 3), 256, 0, stream>>>(p);
    attn_mfma_kernel<<<dim3(S_ / 64, B_ * H_), 256, 0, stream>>>(qhi, qlo, khi, klo, vhi, vlo, hidden);
    gemm_out_kernel<<<dim3(M_ / 64, HID_ / 64), 256, 0, stream>>>(hidden, Wo, bo, out);
}